// Round 2
// baseline (778.781 us; speedup 1.0000x reference)
//
#include <hip/hip_runtime.h>
#include <hip/hip_bf16.h>
#include <cstdint>
#include <math.h>

// Problem constants
#define SEQ 1024
#define DIM 2560
#define HD 128
#define NH 20
#define NKV 5
#define QKV_OUT 3840
#define GS 128

typedef __bf16 bf16;
typedef __bf16 bf16x4 __attribute__((ext_vector_type(4)));
typedef __bf16 bf16x8 __attribute__((ext_vector_type(8)));
typedef float f32x4 __attribute__((ext_vector_type(4)));

// ---------------------------------------------------------------------------
// 1) per-token activation quant: s = 127/clip(amax,1e-5); q=clip(round(x*s));
//    store q as bf16 (ints <=128 are exact in bf16), rs = 1/s
// ---------------------------------------------------------------------------
__global__ __launch_bounds__(256) void quant_kernel(
    const float* __restrict__ x, bf16* __restrict__ act,
    float* __restrict__ rs, int cols) {
  const int row = blockIdx.x;
  const int tid = threadIdx.x;
  const float* xr = x + (size_t)row * cols;
  float m = 0.f;
  for (int i = tid; i < cols; i += 256) m = fmaxf(m, fabsf(xr[i]));
  for (int off = 32; off; off >>= 1) m = fmaxf(m, __shfl_xor(m, off));
  __shared__ float red[4];
  __shared__ float s_bc;
  if ((tid & 63) == 0) red[tid >> 6] = m;
  __syncthreads();
  if (tid == 0) {
    float mm = fmaxf(fmaxf(red[0], red[1]), fmaxf(red[2], red[3]));
    mm = fmaxf(mm, 1e-5f);
    s_bc = 127.f / mm;
    rs[row] = mm / 127.f;
  }
  __syncthreads();
  const float s = s_bc;
  bf16* ar = act + (size_t)row * cols;
  for (int i = tid; i < cols; i += 256) {
    float q = rintf(xr[i] * s);              // round half-to-even like jnp.round
    q = fminf(fmaxf(q, -128.f), 127.f);
    ar[i] = (bf16)q;                         // exact
  }
}

// ---------------------------------------------------------------------------
// 2) weight dequant: wdq[o,k] = bf16(w[o,k] * ws[o, k/128])
// ---------------------------------------------------------------------------
__global__ __launch_bounds__(256) void dequant_kernel(
    const float* __restrict__ w, const float* __restrict__ ws,
    bf16* __restrict__ wdq, int K, long total4) {
  long i = (long)blockIdx.x * 256 + threadIdx.x;
  if (i >= total4) return;
  long e = i * 4;
  int row = (int)(e / K);
  int k = (int)(e % K);
  float sc = ws[(size_t)row * (K / GS) + (k / GS)];
  float4 wv = *(const float4*)(w + e);
  bf16x4 o;
  o[0] = (bf16)(wv.x * sc);
  o[1] = (bf16)(wv.y * sc);
  o[2] = (bf16)(wv.z * sc);
  o[3] = (bf16)(wv.w * sc);
  *(bf16x4*)(wdq + e) = o;
}

// ---------------------------------------------------------------------------
// 3) bf16 MFMA GEMM, C[m,n] = (sum_k A[m,k]*B[n,k]) * rs[m]
//    128x128 tile / block (256 thr = 4 waves, each 64x64), BK=64,
//    global_load_lds width-16 staging (m97 structure).
// ---------------------------------------------------------------------------
__device__ __forceinline__ void gload_lds16(const bf16* g, bf16* l) {
  __builtin_amdgcn_global_load_lds(
      (const __attribute__((address_space(1))) void*)g,
      (__attribute__((address_space(3))) void*)l, 16, 0, 0);
}

template <int OUT_BF16>
__global__ __launch_bounds__(256) void gemm_bt(
    const bf16* __restrict__ A, const bf16* __restrict__ B,
    const float* __restrict__ rs, void* __restrict__ C, int N, int K) {
  __shared__ bf16 As[128 * 64];
  __shared__ bf16 Bs[128 * 64];
  const int tid = threadIdx.x;
  const int w = tid >> 6, l = tid & 63;
  const int row0 = blockIdx.y * 128;
  const int col0 = blockIdx.x * 128;
  const int wm = (w >> 1) * 64, wn = (w & 1) * 64;
  const int lcol = l & 15, quad = l >> 4;
  const int sr = l >> 3;           // row within wave's 8-row slab
  const int sk = (l & 7) * 8;      // k element offset (8 bf16 = 16B)
  const bf16* Ag = A + (size_t)row0 * K;
  const bf16* Bg = B + (size_t)col0 * K;

  f32x4 acc[4][4] = {};

  for (int k0 = 0; k0 < K; k0 += 64) {
    __syncthreads();   // previous compute done before LDS overwrite
#pragma unroll
    for (int i = 0; i < 4; ++i) {
      int r = i * 32 + w * 8 + sr;
      gload_lds16(Ag + (size_t)r * K + k0 + sk, As + (i * 32 + w * 8) * 64);
    }
#pragma unroll
    for (int i = 0; i < 4; ++i) {
      int r = i * 32 + w * 8 + sr;
      gload_lds16(Bg + (size_t)r * K + k0 + sk, Bs + (i * 32 + w * 8) * 64);
    }
    __syncthreads();   // compiler drains vmcnt before barrier
#pragma unroll
    for (int ks = 0; ks < 2; ++ks) {
      const int kk = ks * 32 + quad * 8;
      bf16x8 af[4], bff[4];
#pragma unroll
      for (int mi = 0; mi < 4; ++mi)
        af[mi] = *(const bf16x8*)(As + (wm + mi * 16 + lcol) * 64 + kk);
#pragma unroll
      for (int ni = 0; ni < 4; ++ni)
        bff[ni] = *(const bf16x8*)(Bs + (wn + ni * 16 + lcol) * 64 + kk);
#pragma unroll
      for (int mi = 0; mi < 4; ++mi)
#pragma unroll
        for (int ni = 0; ni < 4; ++ni)
          acc[mi][ni] = __builtin_amdgcn_mfma_f32_16x16x32_bf16(
              af[mi], bff[ni], acc[mi][ni], 0, 0, 0);
    }
  }
  // epilogue: C/D layout col=lane&15, row=quad*4+reg
#pragma unroll
  for (int mi = 0; mi < 4; ++mi) {
#pragma unroll
    for (int ni = 0; ni < 4; ++ni) {
      int col = col0 + wn + ni * 16 + lcol;
#pragma unroll
      for (int r = 0; r < 4; ++r) {
        int row = row0 + wm + mi * 16 + quad * 4 + r;
        float v = acc[mi][ni][r] * rs[row];
        if (OUT_BF16)
          ((bf16*)C)[(size_t)row * N + col] = (bf16)v;
        else
          ((float*)C)[(size_t)row * N + col] = v;
      }
    }
  }
}

// ---------------------------------------------------------------------------
// 4) qkv postprocess: rmsnorm (q,k) + rope (q,k), scatter to Q/K/V layouts
//    grid (SEQ, 30): h<20 -> q head, 20..24 -> k head, 25..29 -> v head
//    64 threads; thread i owns pair (2i, 2i+1)
// ---------------------------------------------------------------------------
__global__ void qkv_post(const float* __restrict__ qkv,
                         const float* __restrict__ qw, const float* __restrict__ kw,
                         float* __restrict__ Qo, float* __restrict__ Ko,
                         float* __restrict__ Vo) {
  const int t = blockIdx.x, h = blockIdx.y, i = threadIdx.x;
  const float* src;
  if (h < NH)       src = qkv + (size_t)t * QKV_OUT + h * HD;
  else if (h < 25)  src = qkv + (size_t)t * QKV_OUT + 2560 + (h - NH) * HD;
  else              src = qkv + (size_t)t * QKV_OUT + 3200 + (h - 25) * HD;
  float x0 = src[2 * i], x1 = src[2 * i + 1];
  if (h < 25) {
    float ss = x0 * x0 + x1 * x1;
    for (int off = 1; off < 64; off <<= 1) ss += __shfl_xor(ss, off);
    float r = rsqrtf(ss * (1.f / 128.f) + 1e-5f);
    const float* wv = (h < NH) ? qw : kw;
    float y0 = x0 * r * wv[2 * i];
    float y1 = x1 * r * wv[2 * i + 1];
    float inv_freq = powf(500000.f, -(float)(2 * i) * (1.f / 128.f));
    float ang = (float)t * inv_freq;
    float sn, cs;
    sincosf(ang, &sn, &cs);
    float o0 = y0 * cs - y1 * sn;
    float o1 = y0 * sn + y1 * cs;
    if (h < NH) {
      float* dst = Qo + ((size_t)t * NH + h) * HD;
      dst[2 * i] = o0; dst[2 * i + 1] = o1;
    } else {
      float* dst = Ko + ((size_t)(h - NH) * SEQ + t) * HD;
      dst[2 * i] = o0; dst[2 * i + 1] = o1;
    }
  } else {
    float* dst = Vo + ((size_t)(h - 25) * SEQ + t) * HD;
    dst[2 * i] = x0; dst[2 * i + 1] = x1;
  }
}

// ---------------------------------------------------------------------------
// 5) GQA causal flash attention (fp32 VALU, 32x32 tiles)
//    grid (32 q-tiles, 20 heads), 256 threads.
//    thread (qr=tid/8, kg=tid%8): 4 scores per tile; owns out dims kg*16..+15
// ---------------------------------------------------------------------------
__global__ __launch_bounds__(256) void attn_kernel(
    const float* __restrict__ Q, const float* __restrict__ Kb,
    const float* __restrict__ Vb, float* __restrict__ O) {
  const int H = blockIdx.y, g = H >> 2, qt = blockIdx.x;
  const int r0 = qt * 32;
  __shared__ float Qs[32][132];
  __shared__ float Ks[32][132];
  __shared__ float Vs[32][132];
  __shared__ float Ps[32][32];
  const int tid = threadIdx.x;
  const int qr = tid >> 3, kg = tid & 7;
  {
    int rr = tid >> 3, c0 = (tid & 7) * 16;
    const float* qp = Q + ((size_t)(r0 + rr) * NH + H) * HD + c0;
#pragma unroll
    for (int j = 0; j < 16; j += 4)
      *(float4*)&Qs[rr][c0 + j] = *(const float4*)(qp + j);
  }
  float mrow = -1e30f, lrow = 0.f;
  float o[16];
#pragma unroll
  for (int j = 0; j < 16; ++j) o[j] = 0.f;
  const float scale = 0.08838834764831843f;

  for (int kt = 0; kt <= qt; ++kt) {
    {
      int rr = tid >> 3, c0 = (tid & 7) * 16;
      const float* kp = Kb + ((size_t)g * SEQ + kt * 32 + rr) * HD + c0;
      const float* vp = Vb + ((size_t)g * SEQ + kt * 32 + rr) * HD + c0;
#pragma unroll
      for (int j = 0; j < 16; j += 4) {
        *(float4*)&Ks[rr][c0 + j] = *(const float4*)(kp + j);
        *(float4*)&Vs[rr][c0 + j] = *(const float4*)(vp + j);
      }
    }
    __syncthreads();
    float sc[4] = {0.f, 0.f, 0.f, 0.f};
    for (int dd = 0; dd < HD; dd += 4) {
      float4 qv = *(const float4*)&Qs[qr][dd];
#pragma unroll
      for (int j = 0; j < 4; ++j) {
        float4 kv = *(const float4*)&Ks[kg * 4 + j][dd];
        sc[j] += qv.x * kv.x + qv.y * kv.y + qv.z * kv.z + qv.w * kv.w;
      }
    }
    const int Rrow = r0 + qr;
    float mt = -1e30f;
#pragma unroll
    for (int j = 0; j < 4; ++j) {
      int cc = kt * 32 + kg * 4 + j;
      sc[j] = (cc <= Rrow) ? sc[j] * scale : -1e30f;
      mt = fmaxf(mt, sc[j]);
    }
    for (int off = 1; off < 8; off <<= 1) mt = fmaxf(mt, __shfl_xor(mt, off));
    float mnew = fmaxf(mrow, mt);
    float alpha = __expf(mrow - mnew);
    float psum = 0.f;
#pragma unroll
    for (int j = 0; j < 4; ++j) {
      float p = __expf(sc[j] - mnew);
      Ps[qr][kg * 4 + j] = p;
      psum += p;
    }
    for (int off = 1; off < 8; off <<= 1) psum += __shfl_xor(psum, off);
    lrow = lrow * alpha + psum;
    mrow = mnew;
#pragma unroll
    for (int j = 0; j < 16; ++j) o[j] *= alpha;
    // Ps produced & consumed by the same 8 lanes of a wave -> no barrier needed
    for (int kc = 0; kc < 32; ++kc) {
      float p = Ps[qr][kc];
      const float* vr = &Vs[kc][kg * 16];
#pragma unroll
      for (int j = 0; j < 16; j += 4) {
        float4 vv = *(const float4*)(vr + j);
        o[j] += p * vv.x; o[j + 1] += p * vv.y;
        o[j + 2] += p * vv.z; o[j + 3] += p * vv.w;
      }
    }
    __syncthreads();   // before next K/V overwrite
  }
  float inv = 1.f / lrow;
  float* op = O + (size_t)(r0 + qr) * DIM + H * HD + kg * 16;
#pragma unroll
  for (int j = 0; j < 16; j += 4) {
    float4 vv = make_float4(o[j] * inv, o[j + 1] * inv, o[j + 2] * inv, o[j + 3] * inv);
    *(float4*)(op + j) = vv;
  }
}

// ---------------------------------------------------------------------------
extern "C" void kernel_launch(void* const* d_in, const int* in_sizes, int n_in,
                              void* d_out, int out_size, void* d_ws, size_t ws_size,
                              hipStream_t stream) {
  const float* x      = (const float*)d_in[0];
  const float* w_qkv  = (const float*)d_in[1];
  const float* ws_qkv = (const float*)d_in[2];
  const float* w_o    = (const float*)d_in[3];
  const float* ws_o   = (const float*)d_in[4];
  const float* qnw    = (const float*)d_in[5];
  const float* knw    = (const float*)d_in[6];
  float* out = (float*)d_out;   // reference output dtype is float32

  char* p = (char*)d_ws;
  bf16*  act1 = (bf16*)p;  p += (size_t)SEQ * DIM * 2;        // 5 MB
  float* rs1  = (float*)p; p += 4096;
  bf16*  wqdq = (bf16*)p;  p += (size_t)QKV_OUT * DIM * 2;    // 19.7 MB
  bf16*  wodq = (bf16*)p;  p += (size_t)DIM * DIM * 2;        // 13.1 MB
  float* qkv  = (float*)p; p += (size_t)SEQ * QKV_OUT * 4;    // 15.7 MB
  float* Qb   = (float*)p; p += (size_t)SEQ * NH * HD * 4;    // 10.5 MB
  float* Kb   = (float*)p; p += (size_t)NKV * SEQ * HD * 4;   // 2.6 MB
  float* Vb   = (float*)p; p += (size_t)NKV * SEQ * HD * 4;   // 2.6 MB
  float* attn = (float*)p; p += (size_t)SEQ * DIM * 4;        // 10.5 MB
  bf16*  act2 = (bf16*)p;  p += (size_t)SEQ * DIM * 2;        // 5 MB
  float* rs2  = (float*)p; p += 4096;                          // ~85 MB total

  quant_kernel<<<SEQ, 256, 0, stream>>>(x, act1, rs1, DIM);
  {
    long t4 = (long)QKV_OUT * DIM / 4;
    dequant_kernel<<<(int)((t4 + 255) / 256), 256, 0, stream>>>(w_qkv, ws_qkv, wqdq, DIM, t4);
  }
  {
    long t4 = (long)DIM * DIM / 4;
    dequant_kernel<<<(int)((t4 + 255) / 256), 256, 0, stream>>>(w_o, ws_o, wodq, DIM, t4);
  }
  gemm_bt<0><<<dim3(QKV_OUT / 128, SEQ / 128), 256, 0, stream>>>(act1, wqdq, rs1, qkv, QKV_OUT, DIM);
  qkv_post<<<dim3(SEQ, 30), 64, 0, stream>>>(qkv, qnw, knw, Qb, Kb, Vb);
  attn_kernel<<<dim3(SEQ / 32, NH), 256, 0, stream>>>(Qb, Kb, Vb, attn);
  quant_kernel<<<SEQ, 256, 0, stream>>>(attn, act2, rs2, DIM);
  gemm_bt<0><<<dim3(DIM / 128, SEQ / 128), 256, 0, stream>>>(act2, wodq, rs2, out, DIM, DIM);
}

// Round 3
// 387.201 us; speedup vs baseline: 2.0113x; 2.0113x over previous
//
#include <hip/hip_runtime.h>
#include <hip/hip_bf16.h>
#include <cstdint>
#include <math.h>

// Problem constants
#define SEQ 1024
#define DIM 2560
#define HD 128
#define NH 20
#define NKV 5
#define QKV_OUT 3840
#define GS 128

typedef __bf16 bf16;
typedef __bf16 bf16x4 __attribute__((ext_vector_type(4)));
typedef __bf16 bf16x8 __attribute__((ext_vector_type(8)));
typedef float f32x4 __attribute__((ext_vector_type(4)));

// ---------------------------------------------------------------------------
// 1) per-token activation quant: s = 127/clip(amax,1e-5); q=clip(round(x*s));
//    store q as bf16 (ints <=128 exact in bf16), rs = 1/s
// ---------------------------------------------------------------------------
__global__ __launch_bounds__(256) void quant_kernel(
    const float* __restrict__ x, bf16* __restrict__ act,
    float* __restrict__ rs, int cols) {
  const int row = blockIdx.x;
  const int tid = threadIdx.x;
  const float* xr = x + (size_t)row * cols;
  float m = 0.f;
  for (int i = tid; i < cols; i += 256) m = fmaxf(m, fabsf(xr[i]));
  for (int off = 32; off; off >>= 1) m = fmaxf(m, __shfl_xor(m, off));
  __shared__ float red[4];
  __shared__ float s_bc;
  if ((tid & 63) == 0) red[tid >> 6] = m;
  __syncthreads();
  if (tid == 0) {
    float mm = fmaxf(fmaxf(red[0], red[1]), fmaxf(red[2], red[3]));
    mm = fmaxf(mm, 1e-5f);
    s_bc = 127.f / mm;
    rs[row] = mm / 127.f;
  }
  __syncthreads();
  const float s = s_bc;
  bf16* ar = act + (size_t)row * cols;
  for (int i = tid; i < cols; i += 256) {
    float q = rintf(xr[i] * s);
    q = fminf(fmaxf(q, -128.f), 127.f);
    ar[i] = (bf16)q;
  }
}

// ---------------------------------------------------------------------------
// 2) weight dequant: wdq[o,k] = bf16(w[o,k] * ws[o, k/128])
// ---------------------------------------------------------------------------
__global__ __launch_bounds__(256) void dequant_kernel(
    const float* __restrict__ w, const float* __restrict__ ws,
    bf16* __restrict__ wdq, int K, long total4) {
  long i = (long)blockIdx.x * 256 + threadIdx.x;
  if (i >= total4) return;
  long e = i * 4;
  int row = (int)(e / K);
  int k = (int)(e % K);
  float sc = ws[(size_t)row * (K / GS) + (k / GS)];
  float4 wv = *(const float4*)(w + e);
  bf16x4 o;
  o[0] = (bf16)(wv.x * sc);
  o[1] = (bf16)(wv.y * sc);
  o[2] = (bf16)(wv.z * sc);
  o[3] = (bf16)(wv.w * sc);
  *(bf16x4*)(wdq + e) = o;
}

// ---------------------------------------------------------------------------
// 3) bf16 MFMA GEMM, C[m,n] = (sum_k A[m,k]*B[n,k]) * rs[m]  (m97 structure)
// ---------------------------------------------------------------------------
__device__ __forceinline__ void gload_lds16(const bf16* g, bf16* l) {
  __builtin_amdgcn_global_load_lds(
      (const __attribute__((address_space(1))) void*)g,
      (__attribute__((address_space(3))) void*)l, 16, 0, 0);
}

template <int OUT_BF16>
__global__ __launch_bounds__(256) void gemm_bt(
    const bf16* __restrict__ A, const bf16* __restrict__ B,
    const float* __restrict__ rs, void* __restrict__ C, int N, int K) {
  __shared__ bf16 As[128 * 64];
  __shared__ bf16 Bs[128 * 64];
  const int tid = threadIdx.x;
  const int w = tid >> 6, l = tid & 63;
  const int row0 = blockIdx.y * 128;
  const int col0 = blockIdx.x * 128;
  const int wm = (w >> 1) * 64, wn = (w & 1) * 64;
  const int lcol = l & 15, quad = l >> 4;
  const int sr = l >> 3;
  const int sk = (l & 7) * 8;
  const bf16* Ag = A + (size_t)row0 * K;
  const bf16* Bg = B + (size_t)col0 * K;

  f32x4 acc[4][4] = {};

  for (int k0 = 0; k0 < K; k0 += 64) {
    __syncthreads();
#pragma unroll
    for (int i = 0; i < 4; ++i) {
      int r = i * 32 + w * 8 + sr;
      gload_lds16(Ag + (size_t)r * K + k0 + sk, As + (i * 32 + w * 8) * 64);
    }
#pragma unroll
    for (int i = 0; i < 4; ++i) {
      int r = i * 32 + w * 8 + sr;
      gload_lds16(Bg + (size_t)r * K + k0 + sk, Bs + (i * 32 + w * 8) * 64);
    }
    __syncthreads();
#pragma unroll
    for (int ks = 0; ks < 2; ++ks) {
      const int kk = ks * 32 + quad * 8;
      bf16x8 af[4], bff[4];
#pragma unroll
      for (int mi = 0; mi < 4; ++mi)
        af[mi] = *(const bf16x8*)(As + (wm + mi * 16 + lcol) * 64 + kk);
#pragma unroll
      for (int ni = 0; ni < 4; ++ni)
        bff[ni] = *(const bf16x8*)(Bs + (wn + ni * 16 + lcol) * 64 + kk);
#pragma unroll
      for (int mi = 0; mi < 4; ++mi)
#pragma unroll
        for (int ni = 0; ni < 4; ++ni)
          acc[mi][ni] = __builtin_amdgcn_mfma_f32_16x16x32_bf16(
              af[mi], bff[ni], acc[mi][ni], 0, 0, 0);
    }
  }
#pragma unroll
  for (int mi = 0; mi < 4; ++mi) {
#pragma unroll
    for (int ni = 0; ni < 4; ++ni) {
      int col = col0 + wn + ni * 16 + lcol;
#pragma unroll
      for (int r = 0; r < 4; ++r) {
        int row = row0 + wm + mi * 16 + quad * 4 + r;
        float v = acc[mi][ni][r] * rs[row];
        if (OUT_BF16)
          ((bf16*)C)[(size_t)row * N + col] = (bf16)v;
        else
          ((float*)C)[(size_t)row * N + col] = v;
      }
    }
  }
}

// ---------------------------------------------------------------------------
// 4) qkv postprocess: rmsnorm (q,k) + rope (q,k); bf16 outputs.
//    Qo [t][h][d], Ko [g][key][d], Vt [g][d][key] (transposed!)
// ---------------------------------------------------------------------------
__global__ void qkv_post(const float* __restrict__ qkv,
                         const float* __restrict__ qw, const float* __restrict__ kw,
                         bf16* __restrict__ Qo, bf16* __restrict__ Ko,
                         bf16* __restrict__ Vt) {
  const int t = blockIdx.x, h = blockIdx.y, i = threadIdx.x;
  const float* src;
  if (h < NH)       src = qkv + (size_t)t * QKV_OUT + h * HD;
  else if (h < 25)  src = qkv + (size_t)t * QKV_OUT + 2560 + (h - NH) * HD;
  else              src = qkv + (size_t)t * QKV_OUT + 3200 + (h - 25) * HD;
  float x0 = src[2 * i], x1 = src[2 * i + 1];
  if (h < 25) {
    float ss = x0 * x0 + x1 * x1;
    for (int off = 1; off < 64; off <<= 1) ss += __shfl_xor(ss, off);
    float r = rsqrtf(ss * (1.f / 128.f) + 1e-5f);
    const float* wv = (h < NH) ? qw : kw;
    float y0 = x0 * r * wv[2 * i];
    float y1 = x1 * r * wv[2 * i + 1];
    float inv_freq = powf(500000.f, -(float)(2 * i) * (1.f / 128.f));
    float ang = (float)t * inv_freq;
    float sn, cs;
    sincosf(ang, &sn, &cs);
    float o0 = y0 * cs - y1 * sn;
    float o1 = y0 * sn + y1 * cs;
    if (h < NH) {
      bf16* dst = Qo + ((size_t)t * NH + h) * HD + 2 * i;
      dst[0] = (bf16)o0; dst[1] = (bf16)o1;
    } else {
      bf16* dst = Ko + ((size_t)(h - NH) * SEQ + t) * HD + 2 * i;
      dst[0] = (bf16)o0; dst[1] = (bf16)o1;
    }
  } else {
    bf16* dst = Vt + ((size_t)(h - 25) * HD + 2 * i) * SEQ + t;
    dst[0] = (bf16)x0; dst[SEQ] = (bf16)x1;
  }
}

// ---------------------------------------------------------------------------
// 5) MFMA GQA causal flash attention. One wave (64 thr) per (16 q-rows, head).
//    S^T = K·Q^T (A=K,B=Q): C-layout col=lane&15=q, row=quad*4+r=key.
//    PV uses a permuted k-dim (key = mg*16 + quad*4 + r) so the P^T B-frag
//    is built from the lane's own S registers (no LDS, no shuffles); V^T
//    A-frags use the same permutation: two 8B loads per frag.
//    No LDS, no barriers.
// ---------------------------------------------------------------------------
__global__ __launch_bounds__(64) void attn_mfma(
    const bf16* __restrict__ Qb, const bf16* __restrict__ Kb,
    const bf16* __restrict__ Vt, float* __restrict__ O) {
  const int qt = (int)(gridDim.x - 1 - blockIdx.x);   // long blocks first
  const int H = blockIdx.y, g = H >> 2;
  const int lane = threadIdx.x;
  const int qcol = lane & 15;      // q-row within band (B-operand col / C col)
  const int quad = lane >> 4;      // 0..3
  const int q_tok = qt * 16 + qcol;
  const float scale = 0.08838834764831843f;

  // Q B-fragments: B[k=d][n=q]; lane: n=qcol, k = kc*32 + quad*8 + j
  bf16x8 qf[4];
  {
    const bf16* qp = Qb + ((size_t)q_tok * NH + H) * HD + quad * 8;
#pragma unroll
    for (int kc = 0; kc < 4; ++kc) qf[kc] = *(const bf16x8*)(qp + kc * 32);
  }

  float m_i = -1e30f, l_i = 0.f;
  f32x4 o_acc[8] = {};   // O^T: d = mg2*16 + quad*4 + r, q = qcol

  const int kt_max = qt >> 2;       // 64-key tiles
  const bf16* kbase = Kb + (size_t)g * SEQ * HD;
  const bf16* vbase = Vt + (size_t)g * HD * SEQ;

  for (int kt = 0; kt <= kt_max; ++kt) {
    // ---- S^T = K · Q^T : A = K-tile rows (m=key), 4 m-groups of 16 ----
    f32x4 s[4];
#pragma unroll
    for (int mg = 0; mg < 4; ++mg) {
      f32x4 acc = {0.f, 0.f, 0.f, 0.f};
      const bf16* kr = kbase + (size_t)(kt * 64 + mg * 16 + qcol) * HD + quad * 8;
#pragma unroll
      for (int kc = 0; kc < 4; ++kc) {
        bf16x8 kf = *(const bf16x8*)(kr + kc * 32);
        acc = __builtin_amdgcn_mfma_f32_16x16x32_bf16(kf, qf[kc], acc, 0, 0, 0);
      }
      s[mg] = acc;
    }
    // ---- scale + causal mask + online softmax (q = qcol for all regs) ----
    float mt = -1e30f;
#pragma unroll
    for (int mg = 0; mg < 4; ++mg)
#pragma unroll
      for (int r = 0; r < 4; ++r) {
        int key = kt * 64 + mg * 16 + quad * 4 + r;
        float v = (key <= q_tok) ? s[mg][r] * scale : -1e30f;
        s[mg][r] = v;
        mt = fmaxf(mt, v);
      }
    mt = fmaxf(mt, __shfl_xor(mt, 16));
    mt = fmaxf(mt, __shfl_xor(mt, 32));
    float mnew = fmaxf(m_i, mt);
    float alpha = __expf(m_i - mnew);
    float ps = 0.f;
#pragma unroll
    for (int mg = 0; mg < 4; ++mg)
#pragma unroll
      for (int r = 0; r < 4; ++r) {
        float pv = __expf(s[mg][r] - mnew);
        s[mg][r] = pv;
        ps += pv;
      }
    ps += __shfl_xor(ps, 16);
    ps += __shfl_xor(ps, 32);
    l_i = l_i * alpha + ps;
    m_i = mnew;
#pragma unroll
    for (int mg2 = 0; mg2 < 8; ++mg2)
#pragma unroll
      for (int r = 0; r < 4; ++r) o_acc[mg2][r] *= alpha;

    // ---- P^T B-frags from own regs (permuted k: key = mg*16 + quad*4 + r) --
    bf16x8 pb[2];
#pragma unroll
    for (int c = 0; c < 2; ++c)
#pragma unroll
      for (int j = 0; j < 8; ++j)
        pb[c][j] = (bf16)s[c * 2 + (j >> 2)][j & 3];

    // ---- O^T += V^T · P^T : A = V^T (m=d), same k-permutation ----
#pragma unroll
    for (int mg2 = 0; mg2 < 8; ++mg2) {
      const bf16* vr = vbase + (size_t)(mg2 * 16 + qcol) * SEQ + kt * 64;
      f32x4 acc = o_acc[mg2];
#pragma unroll
      for (int c = 0; c < 2; ++c) {
        bf16x4 v0 = *(const bf16x4*)(vr + c * 32 + quad * 4);
        bf16x4 v1 = *(const bf16x4*)(vr + c * 32 + 16 + quad * 4);
        bf16x8 vf;
#pragma unroll
        for (int j = 0; j < 4; ++j) { vf[j] = v0[j]; vf[j + 4] = v1[j]; }
        acc = __builtin_amdgcn_mfma_f32_16x16x32_bf16(vf, pb[c], acc, 0, 0, 0);
      }
      o_acc[mg2] = acc;
    }
  }

  // ---- normalize + store: O[t = q_tok][H*128 + d] ----
  const float inv = 1.f / l_i;
  float* op = O + (size_t)q_tok * DIM + H * HD + quad * 4;
#pragma unroll
  for (int mg2 = 0; mg2 < 8; ++mg2) {
    float4 vv = make_float4(o_acc[mg2][0] * inv, o_acc[mg2][1] * inv,
                            o_acc[mg2][2] * inv, o_acc[mg2][3] * inv);
    *(float4*)(op + mg2 * 16) = vv;
  }
}

// ---------------------------------------------------------------------------
extern "C" void kernel_launch(void* const* d_in, const int* in_sizes, int n_in,
                              void* d_out, int out_size, void* d_ws, size_t ws_size,
                              hipStream_t stream) {
  const float* x      = (const float*)d_in[0];
  const float* w_qkv  = (const float*)d_in[1];
  const float* ws_qkv = (const float*)d_in[2];
  const float* w_o    = (const float*)d_in[3];
  const float* ws_o   = (const float*)d_in[4];
  const float* qnw    = (const float*)d_in[5];
  const float* knw    = (const float*)d_in[6];
  float* out = (float*)d_out;

  char* p = (char*)d_ws;
  bf16*  act1 = (bf16*)p;  p += (size_t)SEQ * DIM * 2;
  float* rs1  = (float*)p; p += 4096;
  bf16*  wqdq = (bf16*)p;  p += (size_t)QKV_OUT * DIM * 2;
  bf16*  wodq = (bf16*)p;  p += (size_t)DIM * DIM * 2;
  float* qkv  = (float*)p; p += (size_t)SEQ * QKV_OUT * 4;
  bf16*  Qb   = (bf16*)p;  p += (size_t)SEQ * NH * HD * 2;
  bf16*  Kb   = (bf16*)p;  p += (size_t)NKV * SEQ * HD * 2;
  bf16*  Vt   = (bf16*)p;  p += (size_t)NKV * HD * SEQ * 2;
  float* attn = (float*)p; p += (size_t)SEQ * DIM * 4;
  bf16*  act2 = (bf16*)p;  p += (size_t)SEQ * DIM * 2;
  float* rs2  = (float*)p; p += 4096;

  quant_kernel<<<SEQ, 256, 0, stream>>>(x, act1, rs1, DIM);
  {
    long t4 = (long)QKV_OUT * DIM / 4;
    dequant_kernel<<<(int)((t4 + 255) / 256), 256, 0, stream>>>(w_qkv, ws_qkv, wqdq, DIM, t4);
  }
  {
    long t4 = (long)DIM * DIM / 4;
    dequant_kernel<<<(int)((t4 + 255) / 256), 256, 0, stream>>>(w_o, ws_o, wodq, DIM, t4);
  }
  gemm_bt<0><<<dim3(QKV_OUT / 128, SEQ / 128), 256, 0, stream>>>(act1, wqdq, rs1, qkv, QKV_OUT, DIM);
  qkv_post<<<dim3(SEQ, 30), 64, 0, stream>>>(qkv, qnw, knw, Qb, Kb, Vt);
  attn_mfma<<<dim3(64, NH), 64, 0, stream>>>(Qb, Kb, Vt, attn);
  quant_kernel<<<SEQ, 256, 0, stream>>>(attn, act2, rs2, DIM);
  gemm_bt<0><<<dim3(DIM / 128, SEQ / 128), 256, 0, stream>>>(act2, wodq, rs2, out, DIM, DIM);
}

// Round 4
// 352.299 us; speedup vs baseline: 2.2106x; 1.0991x over previous
//
#include <hip/hip_runtime.h>
#include <hip/hip_bf16.h>
#include <cstdint>
#include <math.h>

// Problem constants
#define SEQ 1024
#define DIM 2560
#define HD 128
#define NH 20
#define NKV 5
#define QKV_OUT 3840
#define GS 128

typedef __bf16 bf16;
typedef __bf16 bf16x4 __attribute__((ext_vector_type(4)));
typedef __bf16 bf16x8 __attribute__((ext_vector_type(8)));
typedef float f32x4 __attribute__((ext_vector_type(4)));

// ---------------------------------------------------------------------------
// 1) per-token activation quant: s = 127/clip(amax,1e-5); q=clip(round(x*s));
//    store q as bf16 (ints <=128 exact in bf16), rs = 1/s
// ---------------------------------------------------------------------------
__global__ __launch_bounds__(256) void quant_kernel(
    const float* __restrict__ x, bf16* __restrict__ act,
    float* __restrict__ rs, int cols) {
  const int row = blockIdx.x;
  const int tid = threadIdx.x;
  const float* xr = x + (size_t)row * cols;
  float m = 0.f;
  for (int i = tid; i < cols; i += 256) m = fmaxf(m, fabsf(xr[i]));
  for (int off = 32; off; off >>= 1) m = fmaxf(m, __shfl_xor(m, off));
  __shared__ float red[4];
  __shared__ float s_bc;
  if ((tid & 63) == 0) red[tid >> 6] = m;
  __syncthreads();
  if (tid == 0) {
    float mm = fmaxf(fmaxf(red[0], red[1]), fmaxf(red[2], red[3]));
    mm = fmaxf(mm, 1e-5f);
    s_bc = 127.f / mm;
    rs[row] = mm / 127.f;
  }
  __syncthreads();
  const float s = s_bc;
  bf16* ar = act + (size_t)row * cols;
  for (int i = tid; i < cols; i += 256) {
    float q = rintf(xr[i] * s);
    q = fminf(fmaxf(q, -128.f), 127.f);
    ar[i] = (bf16)q;
  }
}

// ---------------------------------------------------------------------------
// 2) weight dequant: wdq[o,k] = bf16(w[o,k] * ws[o, k/128])
// ---------------------------------------------------------------------------
__global__ __launch_bounds__(256) void dequant_kernel(
    const float* __restrict__ w, const float* __restrict__ ws,
    bf16* __restrict__ wdq, int K, long total4) {
  long i = (long)blockIdx.x * 256 + threadIdx.x;
  if (i >= total4) return;
  long e = i * 4;
  int row = (int)(e / K);
  int k = (int)(e % K);
  float sc = ws[(size_t)row * (K / GS) + (k / GS)];
  float4 wv = *(const float4*)(w + e);
  bf16x4 o;
  o[0] = (bf16)(wv.x * sc);
  o[1] = (bf16)(wv.y * sc);
  o[2] = (bf16)(wv.z * sc);
  o[3] = (bf16)(wv.w * sc);
  *(bf16x4*)(wdq + e) = o;
}

// ---------------------------------------------------------------------------
// 3) bf16 MFMA GEMM, C[m,n] = (sum_k A[m,k]*B[n,k]) * rs[m]  (m97 structure)
// ---------------------------------------------------------------------------
__device__ __forceinline__ void gload_lds16(const bf16* g, bf16* l) {
  __builtin_amdgcn_global_load_lds(
      (const __attribute__((address_space(1))) void*)g,
      (__attribute__((address_space(3))) void*)l, 16, 0, 0);
}

template <int OUT_BF16>
__global__ __launch_bounds__(256) void gemm_bt(
    const bf16* __restrict__ A, const bf16* __restrict__ B,
    const float* __restrict__ rs, void* __restrict__ C, int N, int K) {
  __shared__ bf16 As[128 * 64];
  __shared__ bf16 Bs[128 * 64];
  const int tid = threadIdx.x;
  const int w = tid >> 6, l = tid & 63;
  const int row0 = blockIdx.y * 128;
  const int col0 = blockIdx.x * 128;
  const int wm = (w >> 1) * 64, wn = (w & 1) * 64;
  const int lcol = l & 15, quad = l >> 4;
  const int sr = l >> 3;
  const int sk = (l & 7) * 8;
  const bf16* Ag = A + (size_t)row0 * K;
  const bf16* Bg = B + (size_t)col0 * K;

  f32x4 acc[4][4] = {};

  for (int k0 = 0; k0 < K; k0 += 64) {
    __syncthreads();
#pragma unroll
    for (int i = 0; i < 4; ++i) {
      int r = i * 32 + w * 8 + sr;
      gload_lds16(Ag + (size_t)r * K + k0 + sk, As + (i * 32 + w * 8) * 64);
    }
#pragma unroll
    for (int i = 0; i < 4; ++i) {
      int r = i * 32 + w * 8 + sr;
      gload_lds16(Bg + (size_t)r * K + k0 + sk, Bs + (i * 32 + w * 8) * 64);
    }
    __syncthreads();
#pragma unroll
    for (int ks = 0; ks < 2; ++ks) {
      const int kk = ks * 32 + quad * 8;
      bf16x8 af[4], bff[4];
#pragma unroll
      for (int mi = 0; mi < 4; ++mi)
        af[mi] = *(const bf16x8*)(As + (wm + mi * 16 + lcol) * 64 + kk);
#pragma unroll
      for (int ni = 0; ni < 4; ++ni)
        bff[ni] = *(const bf16x8*)(Bs + (wn + ni * 16 + lcol) * 64 + kk);
#pragma unroll
      for (int mi = 0; mi < 4; ++mi)
#pragma unroll
        for (int ni = 0; ni < 4; ++ni)
          acc[mi][ni] = __builtin_amdgcn_mfma_f32_16x16x32_bf16(
              af[mi], bff[ni], acc[mi][ni], 0, 0, 0);
    }
  }
#pragma unroll
  for (int mi = 0; mi < 4; ++mi) {
#pragma unroll
    for (int ni = 0; ni < 4; ++ni) {
      int col = col0 + wn + ni * 16 + lcol;
#pragma unroll
      for (int r = 0; r < 4; ++r) {
        int row = row0 + wm + mi * 16 + quad * 4 + r;
        float v = acc[mi][ni][r] * rs[row];
        if (OUT_BF16)
          ((bf16*)C)[(size_t)row * N + col] = (bf16)v;
        else
          ((float*)C)[(size_t)row * N + col] = v;
      }
    }
  }
}

// ---------------------------------------------------------------------------
// 4a) q/k postprocess: rmsnorm + rope; bf16. Qo [t][h][d], Ko [g][key][d]
// ---------------------------------------------------------------------------
__global__ void qk_post(const float* __restrict__ qkv,
                        const float* __restrict__ qw, const float* __restrict__ kw,
                        bf16* __restrict__ Qo, bf16* __restrict__ Ko) {
  const int t = blockIdx.x, h = blockIdx.y, i = threadIdx.x;
  const float* src = (h < NH)
      ? qkv + (size_t)t * QKV_OUT + h * HD
      : qkv + (size_t)t * QKV_OUT + 2560 + (h - NH) * HD;
  float x0 = src[2 * i], x1 = src[2 * i + 1];
  float ss = x0 * x0 + x1 * x1;
  for (int off = 1; off < 64; off <<= 1) ss += __shfl_xor(ss, off);
  float r = rsqrtf(ss * (1.f / 128.f) + 1e-5f);
  const float* wv = (h < NH) ? qw : kw;
  float y0 = x0 * r * wv[2 * i];
  float y1 = x1 * r * wv[2 * i + 1];
  float inv_freq = powf(500000.f, -(float)(2 * i) * (1.f / 128.f));
  float ang = (float)t * inv_freq;
  float sn, cs;
  sincosf(ang, &sn, &cs);
  float o0 = y0 * cs - y1 * sn;
  float o1 = y0 * sn + y1 * cs;
  if (h < NH) {
    bf16* dst = Qo + ((size_t)t * NH + h) * HD + 2 * i;
    dst[0] = (bf16)o0; dst[1] = (bf16)o1;
  } else {
    bf16* dst = Ko + ((size_t)(h - NH) * SEQ + t) * HD + 2 * i;
    dst[0] = (bf16)o0; dst[1] = (bf16)o1;
  }
}

// ---------------------------------------------------------------------------
// 4b) V transpose: qkv fp32 [t][3200+g*128+d] -> Vt bf16 [g][d][t]
//     LDS tile 64 t x 128 d, padded stride 137; coalesced on both sides.
// ---------------------------------------------------------------------------
__global__ __launch_bounds__(256) void v_post(const float* __restrict__ qkv,
                                              bf16* __restrict__ Vt) {
  const int t0 = blockIdx.x * 64, g = blockIdx.y;
  const int tid = threadIdx.x;
  __shared__ bf16 Ls[64 * 137];
  {
    const int tl = tid >> 4;          // 0..15
    const int d0 = (tid & 15) * 8;    // 0..120
#pragma unroll
    for (int pass = 0; pass < 4; ++pass) {
      int t = pass * 16 + tl;
      const float* src = qkv + (size_t)(t0 + t) * QKV_OUT + 3200 + g * HD + d0;
      float4 a = *(const float4*)src;
      float4 b = *(const float4*)(src + 4);
      bf16* dst = Ls + t * 137 + d0;
      dst[0] = (bf16)a.x; dst[1] = (bf16)a.y; dst[2] = (bf16)a.z; dst[3] = (bf16)a.w;
      dst[4] = (bf16)b.x; dst[5] = (bf16)b.y; dst[6] = (bf16)b.z; dst[7] = (bf16)b.w;
    }
  }
  __syncthreads();
  {
    const int dl = tid >> 3;          // 0..31
    const int tl0 = (tid & 7) * 8;    // 0..56
#pragma unroll
    for (int pass = 0; pass < 4; ++pass) {
      int d = pass * 32 + dl;
      bf16x8 v;
#pragma unroll
      for (int j = 0; j < 8; ++j) v[j] = Ls[(tl0 + j) * 137 + d];
      *(bf16x8*)(Vt + ((size_t)g * HD + d) * SEQ + t0 + tl0) = v;
    }
  }
}

// ---------------------------------------------------------------------------
// 5) MFMA GQA causal flash attention, split-K over key tiles.
//    Block = 256 thr (4 waves) per (16-q band, head). Wave w handles key
//    tiles kt = w, w+4, ... with private online-softmax state; LDS combine.
//    S^T = K·Q^T (C: col=q, row=key); PV k-dim permuted so P^T B-frag comes
//    from the lane's own S registers (no shuffles); V^T A-frags via 2x8B.
// ---------------------------------------------------------------------------
__global__ __launch_bounds__(256) void attn_mfma(
    const bf16* __restrict__ Qb, const bf16* __restrict__ Kb,
    const bf16* __restrict__ Vt, float* __restrict__ O) {
  const int qt = 63 - (int)blockIdx.x;     // long blocks first
  const int H = blockIdx.y, g = H >> 2;
  const int tid = threadIdx.x;
  const int wave = tid >> 6, lane = tid & 63;
  const int qcol = lane & 15, quad = lane >> 4;
  const int q_tok = qt * 16 + qcol;
  const float scale = 0.08838834764831843f;

  bf16x8 qf[4];
  {
    const bf16* qp = Qb + ((size_t)q_tok * NH + H) * HD + quad * 8;
#pragma unroll
    for (int kc = 0; kc < 4; ++kc) qf[kc] = *(const bf16x8*)(qp + kc * 32);
  }

  float m_i = -1e30f, l_i = 0.f;
  f32x4 o_acc[8] = {};
  const int kt_max = qt >> 2;
  const bf16* kbase = Kb + (size_t)g * SEQ * HD;
  const bf16* vbase = Vt + (size_t)g * HD * SEQ;

  for (int kt = wave; kt <= kt_max; kt += 4) {
    // ---- S^T = K · Q^T ----
    f32x4 s[4];
#pragma unroll
    for (int mg = 0; mg < 4; ++mg) {
      f32x4 acc = {0.f, 0.f, 0.f, 0.f};
      const bf16* kr = kbase + (size_t)(kt * 64 + mg * 16 + qcol) * HD + quad * 8;
#pragma unroll
      for (int kc = 0; kc < 4; ++kc) {
        bf16x8 kf = *(const bf16x8*)(kr + kc * 32);
        acc = __builtin_amdgcn_mfma_f32_16x16x32_bf16(kf, qf[kc], acc, 0, 0, 0);
      }
      s[mg] = acc;
    }
    // ---- V prefetch (independent of softmax) ----
    bf16x8 vf[8][2];
#pragma unroll
    for (int mg2 = 0; mg2 < 8; ++mg2) {
      const bf16* vr = vbase + (size_t)(mg2 * 16 + qcol) * SEQ + kt * 64;
#pragma unroll
      for (int c = 0; c < 2; ++c) {
        bf16x4 v0 = *(const bf16x4*)(vr + c * 32 + quad * 4);
        bf16x4 v1 = *(const bf16x4*)(vr + c * 32 + 16 + quad * 4);
#pragma unroll
        for (int j = 0; j < 4; ++j) { vf[mg2][c][j] = v0[j]; vf[mg2][c][j + 4] = v1[j]; }
      }
    }
    // ---- scale + causal mask + online softmax ----
    float mt = -1e30f;
#pragma unroll
    for (int mg = 0; mg < 4; ++mg)
#pragma unroll
      for (int r = 0; r < 4; ++r) {
        int key = kt * 64 + mg * 16 + quad * 4 + r;
        float v = (key <= q_tok) ? s[mg][r] * scale : -1e30f;
        s[mg][r] = v;
        mt = fmaxf(mt, v);
      }
    mt = fmaxf(mt, __shfl_xor(mt, 16));
    mt = fmaxf(mt, __shfl_xor(mt, 32));
    float mnew = fmaxf(m_i, mt);
    float alpha = __expf(m_i - mnew);
    float ps = 0.f;
#pragma unroll
    for (int mg = 0; mg < 4; ++mg)
#pragma unroll
      for (int r = 0; r < 4; ++r) {
        float pv = __expf(s[mg][r] - mnew);
        s[mg][r] = pv;
        ps += pv;
      }
    ps += __shfl_xor(ps, 16);
    ps += __shfl_xor(ps, 32);
    l_i = l_i * alpha + ps;
    m_i = mnew;
#pragma unroll
    for (int mg2 = 0; mg2 < 8; ++mg2)
#pragma unroll
      for (int r = 0; r < 4; ++r) o_acc[mg2][r] *= alpha;

    // ---- P^T B-frags from own regs (key = mg*16 + quad*4 + r) ----
    bf16x8 pb[2];
#pragma unroll
    for (int c = 0; c < 2; ++c)
#pragma unroll
      for (int j = 0; j < 8; ++j)
        pb[c][j] = (bf16)s[c * 2 + (j >> 2)][j & 3];

    // ---- O^T += V^T · P^T ----
#pragma unroll
    for (int mg2 = 0; mg2 < 8; ++mg2) {
      f32x4 acc = o_acc[mg2];
#pragma unroll
      for (int c = 0; c < 2; ++c)
        acc = __builtin_amdgcn_mfma_f32_16x16x32_bf16(vf[mg2][c], pb[c], acc, 0, 0, 0);
      o_acc[mg2] = acc;
    }
  }

  // ---- cross-wave combine via LDS ----
  __shared__ float Osh[4 * 16 * 132];   // [w][qcol*132 + d]
  __shared__ float msh[4][16], lsh[4][16];
#pragma unroll
  for (int mg2 = 0; mg2 < 8; ++mg2)
#pragma unroll
    for (int r = 0; r < 4; ++r)
      Osh[wave * 2112 + qcol * 132 + mg2 * 16 + quad * 4 + r] = o_acc[mg2][r];
  if (quad == 0) { msh[wave][qcol] = m_i; lsh[wave][qcol] = l_i; }
  __syncthreads();

  const int ql = tid >> 4;            // 0..15
  const int d0 = (tid & 15) * 8;      // 0..120
  float mg_ = -1e30f;
#pragma unroll
  for (int w2 = 0; w2 < 4; ++w2) mg_ = fmaxf(mg_, msh[w2][ql]);
  float ew[4], lg = 0.f;
#pragma unroll
  for (int w2 = 0; w2 < 4; ++w2) {
    ew[w2] = __expf(msh[w2][ql] - mg_);
    lg += ew[w2] * lsh[w2][ql];
  }
  const float inv = 1.f / lg;
  float res[8];
#pragma unroll
  for (int j = 0; j < 8; ++j) {
    float acc = 0.f;
#pragma unroll
    for (int w2 = 0; w2 < 4; ++w2)
      acc += ew[w2] * Osh[w2 * 2112 + ql * 132 + d0 + j];
    res[j] = acc * inv;
  }
  float* op = O + (size_t)(qt * 16 + ql) * DIM + H * HD + d0;
  *(float4*)op = make_float4(res[0], res[1], res[2], res[3]);
  *(float4*)(op + 4) = make_float4(res[4], res[5], res[6], res[7]);
}

// ---------------------------------------------------------------------------
extern "C" void kernel_launch(void* const* d_in, const int* in_sizes, int n_in,
                              void* d_out, int out_size, void* d_ws, size_t ws_size,
                              hipStream_t stream) {
  const float* x      = (const float*)d_in[0];
  const float* w_qkv  = (const float*)d_in[1];
  const float* ws_qkv = (const float*)d_in[2];
  const float* w_o    = (const float*)d_in[3];
  const float* ws_o   = (const float*)d_in[4];
  const float* qnw    = (const float*)d_in[5];
  const float* knw    = (const float*)d_in[6];
  float* out = (float*)d_out;

  char* p = (char*)d_ws;
  bf16*  act1 = (bf16*)p;  p += (size_t)SEQ * DIM * 2;
  float* rs1  = (float*)p; p += 4096;
  bf16*  wqdq = (bf16*)p;  p += (size_t)QKV_OUT * DIM * 2;
  bf16*  wodq = (bf16*)p;  p += (size_t)DIM * DIM * 2;
  float* qkv  = (float*)p; p += (size_t)SEQ * QKV_OUT * 4;
  bf16*  Qb   = (bf16*)p;  p += (size_t)SEQ * NH * HD * 2;
  bf16*  Kb   = (bf16*)p;  p += (size_t)NKV * SEQ * HD * 2;
  bf16*  Vt   = (bf16*)p;  p += (size_t)NKV * HD * SEQ * 2;
  float* attn = (float*)p; p += (size_t)SEQ * DIM * 4;
  bf16*  act2 = (bf16*)p;  p += (size_t)SEQ * DIM * 2;
  float* rs2  = (float*)p; p += 4096;

  quant_kernel<<<SEQ, 256, 0, stream>>>(x, act1, rs1, DIM);
  {
    long t4 = (long)QKV_OUT * DIM / 4;
    dequant_kernel<<<(int)((t4 + 255) / 256), 256, 0, stream>>>(w_qkv, ws_qkv, wqdq, DIM, t4);
  }
  {
    long t4 = (long)DIM * DIM / 4;
    dequant_kernel<<<(int)((t4 + 255) / 256), 256, 0, stream>>>(w_o, ws_o, wodq, DIM, t4);
  }
  gemm_bt<0><<<dim3(QKV_OUT / 128, SEQ / 128), 256, 0, stream>>>(act1, wqdq, rs1, qkv, QKV_OUT, DIM);
  qk_post<<<dim3(SEQ, 25), 64, 0, stream>>>(qkv, qnw, knw, Qb, Kb);
  v_post<<<dim3(SEQ / 64, NKV), 256, 0, stream>>>(qkv, Vt);
  attn_mfma<<<dim3(64, NH), 256, 0, stream>>>(Qb, Kb, Vt, attn);
  quant_kernel<<<SEQ, 256, 0, stream>>>(attn, act2, rs2, DIM);
  gemm_bt<0><<<dim3(DIM / 128, SEQ / 128), 256, 0, stream>>>(act2, wodq, rs2, out, DIM, DIM);
}